// Round 10
// baseline (165.764 us; speedup 1.0000x reference)
//
#include <hip/hip_runtime.h>
#include <math.h>

#define NB 8
#define NC 256
#define NHW 1024
#define NHEADS 8
#define HD 32

typedef _Float16 half_t;
typedef __attribute__((ext_vector_type(8))) _Float16 half8;
typedef __attribute__((ext_vector_type(4))) _Float16 half4v;
typedef __attribute__((ext_vector_type(2))) _Float16 half2v;
typedef __attribute__((ext_vector_type(4))) float floatx4;

__device__ __forceinline__ half2v pk2(float a, float b) {
    union {
        __fp16 __attribute__((ext_vector_type(2))) r;
        half2v h;
    } u;
    u.r = __builtin_amdgcn_cvt_pkrtz(a, b);  // v_cvt_pkrtz_f16_f32
    return u.h;
}
__device__ __forceinline__ void st8h(half_t* p, half2v a, half2v b) {
    union { half2v h[2]; uint2 u; } t;
    t.h[0] = a; t.h[1] = b;
    *(uint2*)p = t.u;  // 8B store, p must be 8B-aligned
}

// ---------------- weight prep: fp32 -> f16 once (Wq pre-scaled by 1/sqrt(32)*log2e) ----
// 4 matrices of 256x256 contiguous in Wh: [q][k][v][p]. 1 MB read, 512 KB write, ~3 us.
__global__ __launch_bounds__(256) void wprep(
    const float* __restrict__ Wq, const float* __restrict__ Wk,
    const float* __restrict__ Wv, const float* __restrict__ Wp,
    half_t* __restrict__ Wh)
{
    int t = blockIdx.x * 256 + threadIdx.x;  // 128 blocks * 256 thr * 8 elems = 262144
    int e = t * 8;
    int m = e >> 16, off = e & 65535;
    const float* src = (m == 0) ? Wq : (m == 1) ? Wk : (m == 2) ? Wv : Wp;
    float sc = (m == 0) ? 0.17677669529663687f * 1.4426950408889634f : 1.f;
    float4 a = *(const float4*)(src + off);
    float4 b = *(const float4*)(src + off + 4);
    union { half2v h2[4]; half8 h8; } u;
    u.h2[0] = pk2(a.x * sc, a.y * sc);
    u.h2[1] = pk2(a.z * sc, a.w * sc);
    u.h2[2] = pk2(b.x * sc, b.y * sc);
    u.h2[3] = pk2(b.z * sc, b.w * sc);
    *(half8*)&Wh[e] = u.h8;
}

// ---------------- QKV (round-3 winner): 64-wide s-tile, one p per block ------
// grid (16, 1, 24), 512 thr / 8 waves. bz = b + 8*p. Block stages x[b][all c][s0..s0+63]
// ONCE -> LDS transposed f16 [s][c] (XOR block-swizzle), wave wv = head wv (32 o x 64 s).
// Q -> Qt[bh][s][d] (scale folded into Wq); K -> Kt[bh][s][d]; V -> Vv[bh][d][s]
__global__ __launch_bounds__(512) void qkv_mfma(
    const float* __restrict__ x, const half_t* __restrict__ Wh,
    const float* __restrict__ bq, const float* __restrict__ bk, const float* __restrict__ bv,
    half_t* __restrict__ Qt, half_t* __restrict__ Kt, half_t* __restrict__ Vv)
{
    // [s][c], stride 264. 8-half blocks XOR-swizzled by ((s>>2)&7): staging b32 writes
    // land 2 lanes/bank (free); b128 reads keep ~2-way.
    __shared__ half_t xs[64][264];

    int bz = blockIdx.z;
    int b = bz & 7, p = bz >> 3;  // wave-uniform
    const half_t* Wf    = Wh + (size_t)p * 65536;
    const float*  bias  = (p == 0) ? bq : (p == 1) ? bk : bv;

    int t = threadIdx.x;
    int s0 = blockIdx.x * 64;
    const float* xb = x + (size_t)b * NC * NHW;

    // stage + transpose + convert: pairs of c rows -> half2 LDS writes (swizzled)
    {
        int sf = t & 15, cp = t >> 4;  // sf: s-group (4 floats), cp: c-pair 0..31
        int sw = (sf & 7) << 3;        // XOR on 8-half block index (bits 3..5 of col)
        #pragma unroll
        for (int pass = 0; pass < 4; pass++) {
            int c = cp * 2 + 64 * pass;
            int cw = c ^ sw;           // c even, sw bits>=3: stays even, 4B-aligned
            float4 a  = *(const float4*)&xb[(size_t)c * NHW + s0 + sf * 4];
            float4 bb = *(const float4*)&xb[(size_t)(c + 1) * NHW + s0 + sf * 4];
            *(half2v*)&xs[sf * 4 + 0][cw] = pk2(a.x, bb.x);
            *(half2v*)&xs[sf * 4 + 1][cw] = pk2(a.y, bb.y);
            *(half2v*)&xs[sf * 4 + 2][cw] = pk2(a.z, bb.z);
            *(half2v*)&xs[sf * 4 + 3][cw] = pk2(a.w, bb.w);
        }
    }
    __syncthreads();

    int wv = t >> 6, lane = t & 63;
    int mm = lane & 15, q = lane >> 4;
    int o0 = wv * 32;  // wave wv == head wv

    floatx4 acc[2][4];
    #pragma unroll
    for (int mt = 0; mt < 2; mt++)
        #pragma unroll
        for (int nt = 0; nt < 4; nt++) acc[mt][nt] = (floatx4){0.f, 0.f, 0.f, 0.f};

    #pragma unroll
    for (int k0 = 0; k0 < NC; k0 += 32) {
        half8 af[2], bf[4];
        #pragma unroll
        for (int mt = 0; mt < 2; mt++)
            af[mt] = *(const half8*)&Wf[(size_t)(o0 + mt * 16 + mm) * NC + k0 + q * 8];
        #pragma unroll
        for (int nt = 0; nt < 4; nt++) {
            int row = nt * 16 + mm;
            int col = (k0 + q * 8) ^ (((row >> 2) & 7) << 3);  // same swizzle as writes
            bf[nt] = *(const half8*)&xs[row][col];
        }
        #pragma unroll
        for (int mt = 0; mt < 2; mt++)
            #pragma unroll
            for (int nt = 0; nt < 4; nt++)
                acc[mt][nt] = __builtin_amdgcn_mfma_f32_16x16x32_f16(af[mt], bf[nt], acc[mt][nt], 0, 0, 0);
    }

    int h  = wv;
    int bh = b * NHEADS + h;
    // Wq was pre-scaled by qs at prep; bias for p==0 must get the same scale.
    const float qs = 0.17677669529663687f * 1.4426950408889634f;
    float bsc = (p == 0) ? qs : 1.f;

    #pragma unroll
    for (int mt = 0; mt < 2; mt++) {
        int d0 = mt * 16 + q * 4;  // d within head
        float bb[4];
        #pragma unroll
        for (int r = 0; r < 4; r++) bb[r] = bias[o0 + mt * 16 + q * 4 + r] * bsc;
        #pragma unroll
        for (int nt = 0; nt < 4; nt++) {
            int s = s0 + nt * 16 + mm;
            float v0 = acc[mt][nt][0] + bb[0], v1 = acc[mt][nt][1] + bb[1];
            float v2 = acc[mt][nt][2] + bb[2], v3 = acc[mt][nt][3] + bb[3];
            if (p < 2) {
                half_t* out = (p == 0 ? Qt : Kt) + ((size_t)bh * NHW + s) * HD + d0;
                st8h(out, pk2(v0, v1), pk2(v2, v3));
            } else {
                Vv[((size_t)bh * HD + d0 + 0) * NHW + s] = (half_t)v0;
                Vv[((size_t)bh * HD + d0 + 1) * NHW + s] = (half_t)v1;
                Vv[((size_t)bh * HD + d0 + 2) * NHW + s] = (half_t)v2;
                Vv[((size_t)bh * HD + d0 + 3) * NHW + s] = (half_t)v3;
            }
        }
    }
}

// ---------------- fused attention: 64 q/block, R7 lagged pipeline + low LDS ------------
// grid 1024. bh = L&63, iblk = L>>6. 4 waves split 1024 keys.
// R9 post-mortem: R8's same-iteration P round-trip serialized the chain (MfmaUtil 4.8%).
// Restored: pf/vp one-iteration lag (PV for it-1 overlaps it's loads+QK), deep K prefetch.
// Kept from R8: single P buffer (write+readback same iter -> no cross-iter LDS dep) and
// ds_add_f32 epilogue: LDS 27.2 KB (vs R7 71.7) -> >=3 blocks/CU.
__global__ __launch_bounds__(256) void attn_mfma(
    const half_t* __restrict__ Qt, const half_t* __restrict__ Kt,
    const half_t* __restrict__ Vv, half_t* __restrict__ At)
{
    __shared__ half_t Pl[4][4][16][36];  // [wave][qt][i][j] 18.4 KB
    __shared__ float Oz[32][66];         // shared accumulator, stride 66 (2-way max) 8.4 KB
    __shared__ float Dz[64];

    int wv = threadIdx.x >> 6, lane = threadIdx.x & 63;
    int mm = lane & 15, q = lane >> 4;
    int L = blockIdx.x;
    int bh = L & 63, iblk = L >> 6;
    int b = bh >> 3, h = bh & 7;
    int i0 = iblk * 64;

    // zero the shared accumulators
    {
        int t = threadIdx.x;
        float* oz = &Oz[0][0];
        for (int idx = t; idx < 32 * 66; idx += 256) oz[idx] = 0.f;
        if (t < 64) Dz[t] = 0.f;
    }
    __syncthreads();

    const half_t* Qb = Qt + (size_t)bh * NHW * HD;
    const half_t* Kb = Kt + (size_t)bh * NHW * HD;
    const half_t* Vb = Vv + (size_t)bh * HD * NHW;

    half8 qf[4];
    #pragma unroll
    for (int qt = 0; qt < 4; qt++)
        qf[qt] = *(const half8*)&Qb[(size_t)(i0 + qt * 16 + mm) * HD + q * 8];

    const int jb = wv * 256;  // this wave's key quarter
    floatx4 zero = (floatx4){0.f, 0.f, 0.f, 0.f};
    floatx4 oa[4][2];
    #pragma unroll
    for (int qt = 0; qt < 4; qt++) { oa[qt][0] = zero; oa[qt][1] = zero; }
    float dd[4] = {0.f, 0.f, 0.f, 0.f};
    const _Float16 z = (_Float16)0.f;
    half8 pf[4];
    #pragma unroll
    for (int qt = 0; qt < 4; qt++) pf[qt] = (half8){z, z, z, z, z, z, z, z};

    half8 kc0 = *(const half8*)&Kb[(size_t)(jb + mm) * HD + q * 8];
    half8 kc1 = *(const half8*)&Kb[(size_t)(jb + 16 + mm) * HD + q * 8];
    half8 kn0 = *(const half8*)&Kb[(size_t)(jb + 32 + mm) * HD + q * 8];
    half8 kn1 = *(const half8*)&Kb[(size_t)(jb + 48 + mm) * HD + q * 8];
    half8 vc0 = *(const half8*)&Vb[(size_t)mm * NHW + jb + q * 8];
    half8 vc1 = *(const half8*)&Vb[(size_t)(16 + mm) * NHW + jb + q * 8];
    half8 vp0 = vc0, vp1 = vc1;

    #pragma unroll
    for (int it = 0; it < 8; it++) {
        // QK^T for current j-block (K held in registers since it-1's prefetch)
        floatx4 s[4][2];
        #pragma unroll
        for (int qt = 0; qt < 4; qt++) {
            s[qt][0] = __builtin_amdgcn_mfma_f32_16x16x32_f16(kc0, qf[qt], zero, 0, 0, 0);
            s[qt][1] = __builtin_amdgcn_mfma_f32_16x16x32_f16(kc1, qf[qt], zero, 0, 0, 0);
        }

        // prefetch K two blocks ahead, V one block ahead
        int jk = jb + ((it + 2) & 7) * 32;
        int jv = jb + ((it + 1) & 7) * 32;
        half8 kf0 = *(const half8*)&Kb[(size_t)(jk + mm) * HD + q * 8];
        half8 kf1 = *(const half8*)&Kb[(size_t)(jk + 16 + mm) * HD + q * 8];
        half8 vn0 = *(const half8*)&Vb[(size_t)mm * NHW + jv + q * 8];
        half8 vn1 = *(const half8*)&Vb[(size_t)(16 + mm) * NHW + jv + q * 8];

        // PV for iteration it-1 (pf read back last iteration; vp = V_{it-1})
        #pragma unroll
        for (int qt = 0; qt < 4; qt++) {
            oa[qt][0] = __builtin_amdgcn_mfma_f32_16x16x32_f16(vp0, pf[qt], oa[qt][0], 0, 0, 0);
            oa[qt][1] = __builtin_amdgcn_mfma_f32_16x16x32_f16(vp1, pf[qt], oa[qt][1], 0, 0, 0);
        }

        #pragma unroll
        for (int qt = 0; qt < 4; qt++) {
            float e0 = exp2f(s[qt][0][0]), e1 = exp2f(s[qt][0][1]);
            float e2 = exp2f(s[qt][0][2]), e3 = exp2f(s[qt][0][3]);
            float f0 = exp2f(s[qt][1][0]), f1 = exp2f(s[qt][1][1]);
            float f2 = exp2f(s[qt][1][2]), f3 = exp2f(s[qt][1][3]);
            dd[qt] += ((e0 + e1) + (e2 + e3)) + ((f0 + f1) + (f2 + f3));
            half_t (*PB)[36] = Pl[wv][qt];
            st8h(&PB[mm][q * 4],      pk2(e0, e1), pk2(e2, e3));
            st8h(&PB[mm][16 + q * 4], pk2(f0, f1), pk2(f2, f3));
        }
        // read back P^T B-fragments now; consumed NEXT iteration (reg pipeline)
        #pragma unroll
        for (int qt = 0; qt < 4; qt++) {
            union { half4v h4[2]; half8 h8; } u;
            u.h4[0] = *(half4v*)&Pl[wv][qt][mm][q * 8];
            u.h4[1] = *(half4v*)&Pl[wv][qt][mm][q * 8 + 4];
            pf[qt] = u.h8;
        }

        kc0 = kn0; kc1 = kn1; kn0 = kf0; kn1 = kf1;
        vp0 = vc0; vp1 = vc1; vc0 = vn0; vc1 = vn1;
    }
    // drain: PV for it=7
    #pragma unroll
    for (int qt = 0; qt < 4; qt++) {
        oa[qt][0] = __builtin_amdgcn_mfma_f32_16x16x32_f16(vp0, pf[qt], oa[qt][0], 0, 0, 0);
        oa[qt][1] = __builtin_amdgcn_mfma_f32_16x16x32_f16(vp1, pf[qt], oa[qt][1], 0, 0, 0);
    }

    #pragma unroll
    for (int qt = 0; qt < 4; qt++) {
        dd[qt] += __shfl_xor(dd[qt], 16);
        dd[qt] += __shfl_xor(dd[qt], 32);
    }
    if (q == 0) {
        #pragma unroll
        for (int qt = 0; qt < 4; qt++) atomicAdd(&Dz[qt * 16 + mm], dd[qt]);
    }
    #pragma unroll
    for (int qt = 0; qt < 4; qt++)
        #pragma unroll
        for (int r = 0; r < 4; r++) {
            atomicAdd(&Oz[q * 4 + r][qt * 16 + mm],      oa[qt][0][r]);
            atomicAdd(&Oz[16 + q * 4 + r][qt * 16 + mm], oa[qt][1][r]);
        }
    __syncthreads();

    int t = threadIdx.x;
    int iloc = t >> 2, dg = t & 3;  // 64 queries x 4 groups of 8 d
    float rinv = 1.f / Dz[iloc];
    float v[8];
    #pragma unroll
    for (int r = 0; r < 8; r++) v[r] = Oz[dg * 8 + r][iloc] * rinv;
    half_t* dst = At + ((size_t)b * NHW + i0 + iloc) * NC + h * HD + dg * 8;
    st8h(dst,     pk2(v[0], v[1]), pk2(v[2], v[3]));
    st8h(dst + 4, pk2(v[4], v[5]), pk2(v[6], v[7]));
}

// ---------------- fused output projection + residual + LayerNorm ----------------
// grid (32, 8) = 256 blocks (1/CU), 512 thr / 8 waves. s-tile 32: halves Wp L2 re-reads.
// Wave w: o-range (w&3)*64, k-half (w>>2)*128.
__global__ __launch_bounds__(512) void projln(
    const half_t* __restrict__ At, const half_t* __restrict__ Wph,
    const float* __restrict__ bp, const float* __restrict__ x,
    const float* __restrict__ gamma, const float* __restrict__ beta,
    float* __restrict__ outp)
{
    __shared__ float tile[32][273];   // [s][c]
    __shared__ float xs[256][33];     // coalesced-staged residual [c][s]
    __shared__ float Pz[4][64][33];   // upper-k-half partials [o-wave][o_loc][s]
    __shared__ float ps[16][32], ps2[16][32];
    __shared__ float mu_s[32], rs_s[32];

    int t = threadIdx.x, wv = t >> 6, lane = t & 63;
    int mm = lane & 15, q = lane >> 4;
    int oh = wv & 3, kh = wv >> 2;
    int o0 = oh * 64;
    int b = blockIdx.y, s0 = blockIdx.x * 32;
    const half_t* ab = At + (size_t)b * NHW * NC;

    {
        int sL = t & 31, cb = t >> 5;  // 16 c-rows per pass
        #pragma unroll
        for (int pass = 0; pass < 16; pass++) {
            int c = pass * 16 + cb;
            xs[c][sL] = x[((size_t)b * NC + c) * NHW + s0 + sL];
        }
    }

    floatx4 acc[4][2];
    #pragma unroll
    for (int mt = 0; mt < 4; mt++)
        #pragma unroll
        for (int nt = 0; nt < 2; nt++) acc[mt][nt] = (floatx4){0.f, 0.f, 0.f, 0.f};

    int kbase = kh * 128;
    #pragma unroll
    for (int kk = 0; kk < 128; kk += 32) {
        int k0 = kbase + kk;
        half8 bf[2];
        #pragma unroll
        for (int nt = 0; nt < 2; nt++)
            bf[nt] = *(const half8*)&ab[(size_t)(s0 + nt * 16 + mm) * NC + k0 + q * 8];
        #pragma unroll
        for (int mt = 0; mt < 4; mt++) {
            half8 af = *(const half8*)&Wph[(size_t)(o0 + mt * 16 + mm) * NC + k0 + q * 8];
            #pragma unroll
            for (int nt = 0; nt < 2; nt++)
                acc[mt][nt] = __builtin_amdgcn_mfma_f32_16x16x32_f16(af, bf[nt], acc[mt][nt], 0, 0, 0);
        }
    }

    if (kh == 1) {
        #pragma unroll
        for (int mt = 0; mt < 4; mt++)
            #pragma unroll
            for (int nt = 0; nt < 2; nt++)
                #pragma unroll
                for (int r = 0; r < 4; r++)
                    Pz[oh][mt * 16 + q * 4 + r][nt * 16 + mm] = acc[mt][nt][r];
    }
    __syncthreads();
    if (kh == 0) {
        #pragma unroll
        for (int mt = 0; mt < 4; mt++) {
            #pragma unroll
            for (int nt = 0; nt < 2; nt++) {
                #pragma unroll
                for (int r = 0; r < 4; r++) {
                    int ol = mt * 16 + q * 4 + r;
                    int o = o0 + ol;
                    int sl = nt * 16 + mm;
                    tile[sl][o] = acc[mt][nt][r] + Pz[oh][ol][sl] + bp[o] + xs[o][sl];
                }
            }
        }
    }
    __syncthreads();

    int sL = t & 31, part = t >> 5;  // 16 parts of 16 channels
    float sum = 0.f, sq = 0.f;
    #pragma unroll
    for (int cc = 0; cc < 16; cc++) {
        float v = tile[sL][part * 16 + cc];
        sum += v; sq += v * v;
    }
    ps[part][sL] = sum; ps2[part][sL] = sq;
    __syncthreads();
    if (t < 32) {
        float S = 0.f, S2 = 0.f;
        #pragma unroll
        for (int p2 = 0; p2 < 16; p2++) { S += ps[p2][t]; S2 += ps2[p2][t]; }
        float mu  = S * (1.f / NC);
        float var = S2 * (1.f / NC) - mu * mu;
        mu_s[t] = mu;
        rs_s[t] = rsqrtf(var + 1e-5f);
    }
    __syncthreads();
    float mu = mu_s[sL], rs = rs_s[sL];
    float* ob = outp + (size_t)b * NC * NHW;
    #pragma unroll
    for (int cc = 0; cc < 16; cc++) {
        int c = part * 16 + cc;
        ob[(size_t)c * NHW + s0 + sL] = (tile[sL][c] - mu) * rs * gamma[c] + beta[c];
    }
}

extern "C" void kernel_launch(void* const* d_in, const int* in_sizes, int n_in,
                              void* d_out, int out_size, void* d_ws, size_t ws_size,
                              hipStream_t stream)
{
    const float* x     = (const float*)d_in[0];
    const float* Wq    = (const float*)d_in[1];
    const float* bq    = (const float*)d_in[2];
    const float* Wk    = (const float*)d_in[3];
    const float* bk    = (const float*)d_in[4];
    const float* Wv    = (const float*)d_in[5];
    const float* bv    = (const float*)d_in[6];
    const float* Wp    = (const float*)d_in[7];
    const float* bp    = (const float*)d_in[8];
    const float* gamma = (const float*)d_in[9];
    const float* beta  = (const float*)d_in[10];
    float* out = (float*)d_out;

    char* w = (char*)d_ws;
    half_t* Qt = (half_t*)(w);                       // 4 MB [bh][s][d]
    half_t* Kt = (half_t*)(w + ((size_t)4  << 20));  // 4 MB [bh][s][d]
    half_t* Vv = (half_t*)(w + ((size_t)8  << 20));  // 4 MB [bh][d][s]
    half_t* At = (half_t*)(w + ((size_t)12 << 20));  // 4 MB [b][s][c]
    half_t* Wh = (half_t*)(w + ((size_t)16 << 20));  // 512 KB f16 weights [q][k][v][p]

    wprep<<<dim3(128), 256, 0, stream>>>(Wq, Wk, Wv, Wp, Wh);
    qkv_mfma<<<dim3(16, 1, 24), 512, 0, stream>>>(x, Wh, bq, bk, bv, Qt, Kt, Vv);
    attn_mfma<<<dim3(1024), 256, 0, stream>>>(Qt, Kt, Vv, At);
    projln<<<dim3(32, 8), 512, 0, stream>>>(At, Wh + 3 * 65536, bp, x, gamma, beta, out);
}

// Round 11
// 128.166 us; speedup vs baseline: 1.2934x; 1.2934x over previous
//
#include <hip/hip_runtime.h>
#include <math.h>

#define NB 8
#define NC 256
#define NHW 1024
#define NHEADS 8
#define HD 32

typedef _Float16 half_t;
typedef __attribute__((ext_vector_type(8))) _Float16 half8;
typedef __attribute__((ext_vector_type(4))) _Float16 half4v;
typedef __attribute__((ext_vector_type(2))) _Float16 half2v;
typedef __attribute__((ext_vector_type(4))) float floatx4;

__device__ __forceinline__ half2v pk2(float a, float b) {
    union {
        __fp16 __attribute__((ext_vector_type(2))) r;
        half2v h;
    } u;
    u.r = __builtin_amdgcn_cvt_pkrtz(a, b);  // v_cvt_pkrtz_f16_f32
    return u.h;
}
__device__ __forceinline__ void st8h(half_t* p, half2v a, half2v b) {
    union { half2v h[2]; uint2 u; } t;
    t.h[0] = a; t.h[1] = b;
    *(uint2*)p = t.u;  // 8B store, p must be 8B-aligned
}

// ---------------- weight prep: fp32 -> f16 once (Wq pre-scaled by 1/sqrt(32)*log2e) ----
// 4 matrices of 256x256 contiguous in Wh: [q][k][v][p]. 1 MB read, 512 KB write, ~3 us.
__global__ __launch_bounds__(256) void wprep(
    const float* __restrict__ Wq, const float* __restrict__ Wk,
    const float* __restrict__ Wv, const float* __restrict__ Wp,
    half_t* __restrict__ Wh)
{
    int t = blockIdx.x * 256 + threadIdx.x;  // 128 blocks * 256 thr * 8 elems = 262144
    int e = t * 8;
    int m = e >> 16, off = e & 65535;
    const float* src = (m == 0) ? Wq : (m == 1) ? Wk : (m == 2) ? Wv : Wp;
    float sc = (m == 0) ? 0.17677669529663687f * 1.4426950408889634f : 1.f;
    float4 a = *(const float4*)(src + off);
    float4 b = *(const float4*)(src + off + 4);
    union { half2v h2[4]; half8 h8; } u;
    u.h2[0] = pk2(a.x * sc, a.y * sc);
    u.h2[1] = pk2(a.z * sc, a.w * sc);
    u.h2[2] = pk2(b.x * sc, b.y * sc);
    u.h2[3] = pk2(b.z * sc, b.w * sc);
    *(half8*)&Wh[e] = u.h8;
}

// ---------------- QKV (round-3 winner): 64-wide s-tile, one p per block ------
// grid (16, 1, 24), 512 thr / 8 waves. bz = b + 8*p. Block stages x[b][all c][s0..s0+63]
// ONCE -> LDS transposed f16 [s][c] (XOR block-swizzle), wave wv = head wv (32 o x 64 s).
// Q -> Qt[bh][s][d] (scale folded into Wq); K -> Kt[bh][s][d]; V -> Vv[bh][d][s]
__global__ __launch_bounds__(512) void qkv_mfma(
    const float* __restrict__ x, const half_t* __restrict__ Wh,
    const float* __restrict__ bq, const float* __restrict__ bk, const float* __restrict__ bv,
    half_t* __restrict__ Qt, half_t* __restrict__ Kt, half_t* __restrict__ Vv)
{
    // [s][c], stride 264. 8-half blocks XOR-swizzled by ((s>>2)&7): staging b32 writes
    // land 2 lanes/bank (free); b128 reads keep ~2-way.
    __shared__ half_t xs[64][264];

    int bz = blockIdx.z;
    int b = bz & 7, p = bz >> 3;  // wave-uniform
    const half_t* Wf    = Wh + (size_t)p * 65536;
    const float*  bias  = (p == 0) ? bq : (p == 1) ? bk : bv;

    int t = threadIdx.x;
    int s0 = blockIdx.x * 64;
    const float* xb = x + (size_t)b * NC * NHW;

    // stage + transpose + convert: pairs of c rows -> half2 LDS writes (swizzled)
    {
        int sf = t & 15, cp = t >> 4;  // sf: s-group (4 floats), cp: c-pair 0..31
        int sw = (sf & 7) << 3;        // XOR on 8-half block index (bits 3..5 of col)
        #pragma unroll
        for (int pass = 0; pass < 4; pass++) {
            int c = cp * 2 + 64 * pass;
            int cw = c ^ sw;           // c even, sw bits>=3: stays even, 4B-aligned
            float4 a  = *(const float4*)&xb[(size_t)c * NHW + s0 + sf * 4];
            float4 bb = *(const float4*)&xb[(size_t)(c + 1) * NHW + s0 + sf * 4];
            *(half2v*)&xs[sf * 4 + 0][cw] = pk2(a.x, bb.x);
            *(half2v*)&xs[sf * 4 + 1][cw] = pk2(a.y, bb.y);
            *(half2v*)&xs[sf * 4 + 2][cw] = pk2(a.z, bb.z);
            *(half2v*)&xs[sf * 4 + 3][cw] = pk2(a.w, bb.w);
        }
    }
    __syncthreads();

    int wv = t >> 6, lane = t & 63;
    int mm = lane & 15, q = lane >> 4;
    int o0 = wv * 32;  // wave wv == head wv

    floatx4 acc[2][4];
    #pragma unroll
    for (int mt = 0; mt < 2; mt++)
        #pragma unroll
        for (int nt = 0; nt < 4; nt++) acc[mt][nt] = (floatx4){0.f, 0.f, 0.f, 0.f};

    #pragma unroll
    for (int k0 = 0; k0 < NC; k0 += 32) {
        half8 af[2], bf[4];
        #pragma unroll
        for (int mt = 0; mt < 2; mt++)
            af[mt] = *(const half8*)&Wf[(size_t)(o0 + mt * 16 + mm) * NC + k0 + q * 8];
        #pragma unroll
        for (int nt = 0; nt < 4; nt++) {
            int row = nt * 16 + mm;
            int col = (k0 + q * 8) ^ (((row >> 2) & 7) << 3);  // same swizzle as writes
            bf[nt] = *(const half8*)&xs[row][col];
        }
        #pragma unroll
        for (int mt = 0; mt < 2; mt++)
            #pragma unroll
            for (int nt = 0; nt < 4; nt++)
                acc[mt][nt] = __builtin_amdgcn_mfma_f32_16x16x32_f16(af[mt], bf[nt], acc[mt][nt], 0, 0, 0);
    }

    int h  = wv;
    int bh = b * NHEADS + h;
    // Wq was pre-scaled by qs at prep; bias for p==0 must get the same scale.
    const float qs = 0.17677669529663687f * 1.4426950408889634f;
    float bsc = (p == 0) ? qs : 1.f;

    #pragma unroll
    for (int mt = 0; mt < 2; mt++) {
        int d0 = mt * 16 + q * 4;  // d within head
        float bb[4];
        #pragma unroll
        for (int r = 0; r < 4; r++) bb[r] = bias[o0 + mt * 16 + q * 4 + r] * bsc;
        #pragma unroll
        for (int nt = 0; nt < 4; nt++) {
            int s = s0 + nt * 16 + mm;
            float v0 = acc[mt][nt][0] + bb[0], v1 = acc[mt][nt][1] + bb[1];
            float v2 = acc[mt][nt][2] + bb[2], v3 = acc[mt][nt][3] + bb[3];
            if (p < 2) {
                half_t* out = (p == 0 ? Qt : Kt) + ((size_t)bh * NHW + s) * HD + d0;
                st8h(out, pk2(v0, v1), pk2(v2, v3));
            } else {
                Vv[((size_t)bh * HD + d0 + 0) * NHW + s] = (half_t)v0;
                Vv[((size_t)bh * HD + d0 + 1) * NHW + s] = (half_t)v1;
                Vv[((size_t)bh * HD + d0 + 2) * NHW + s] = (half_t)v2;
                Vv[((size_t)bh * HD + d0 + 3) * NHW + s] = (half_t)v3;
            }
        }
    }
}

// ---------------- fused attention (exact round-7 best): S^T, j-split, 64 q/block -------
// grid 1024: bh = L&63 (8-head K/V per XCD, L2-resident), iblk = L>>6.
// 4 waves each own a 256-key quarter; lagged reg pipeline (pf/vp); double-buffered Pl;
// per-wave Oz/Dz stores + cross-wave reduce epilogue. Measured <43 us (R7, 128.6 total).
__global__ __launch_bounds__(256) void attn_mfma(
    const half_t* __restrict__ Qt, const half_t* __restrict__ Kt,
    const half_t* __restrict__ Vv, half_t* __restrict__ At)
{
    __shared__ half_t Pl[4][4][2][16][36];  // [wave][qt][buf][i][j] ~36 KB
    __shared__ float Oz[4][32][66];         // [wave][d][i] stride 66: 2-way max ~34 KB
    __shared__ float Dz[4][64];             // [wave][i]

    int wv = threadIdx.x >> 6, lane = threadIdx.x & 63;
    int mm = lane & 15, q = lane >> 4;
    int L = blockIdx.x;
    int bh = L & 63, iblk = L >> 6;
    int b = bh >> 3, h = bh & 7;
    int i0 = iblk * 64;

    const half_t* Qb = Qt + (size_t)bh * NHW * HD;
    const half_t* Kb = Kt + (size_t)bh * NHW * HD;
    const half_t* Vb = Vv + (size_t)bh * HD * NHW;

    half8 qf[4];
    #pragma unroll
    for (int qt = 0; qt < 4; qt++)
        qf[qt] = *(const half8*)&Qb[(size_t)(i0 + qt * 16 + mm) * HD + q * 8];

    const int jb = wv * 256;  // this wave's key quarter
    floatx4 zero = (floatx4){0.f, 0.f, 0.f, 0.f};
    floatx4 oa[4][2];
    #pragma unroll
    for (int qt = 0; qt < 4; qt++) { oa[qt][0] = zero; oa[qt][1] = zero; }
    float dd[4] = {0.f, 0.f, 0.f, 0.f};
    const _Float16 z = (_Float16)0.f;
    half8 pf[4];
    #pragma unroll
    for (int qt = 0; qt < 4; qt++) pf[qt] = (half8){z, z, z, z, z, z, z, z};

    half8 kc0 = *(const half8*)&Kb[(size_t)(jb + mm) * HD + q * 8];
    half8 kc1 = *(const half8*)&Kb[(size_t)(jb + 16 + mm) * HD + q * 8];
    half8 kn0 = *(const half8*)&Kb[(size_t)(jb + 32 + mm) * HD + q * 8];
    half8 kn1 = *(const half8*)&Kb[(size_t)(jb + 48 + mm) * HD + q * 8];
    half8 vc0 = *(const half8*)&Vb[(size_t)mm * NHW + jb + q * 8];
    half8 vc1 = *(const half8*)&Vb[(size_t)(16 + mm) * NHW + jb + q * 8];
    half8 vp0 = vc0, vp1 = vc1;

    #pragma unroll
    for (int it = 0; it < 8; it++) {
        floatx4 s[4][2];
        #pragma unroll
        for (int qt = 0; qt < 4; qt++) {
            s[qt][0] = __builtin_amdgcn_mfma_f32_16x16x32_f16(kc0, qf[qt], zero, 0, 0, 0);
            s[qt][1] = __builtin_amdgcn_mfma_f32_16x16x32_f16(kc1, qf[qt], zero, 0, 0, 0);
        }

        int jk = jb + ((it + 2) & 7) * 32;
        int jv = jb + ((it + 1) & 7) * 32;
        half8 kf0 = *(const half8*)&Kb[(size_t)(jk + mm) * HD + q * 8];
        half8 kf1 = *(const half8*)&Kb[(size_t)(jk + 16 + mm) * HD + q * 8];
        half8 vn0 = *(const half8*)&Vb[(size_t)mm * NHW + jv + q * 8];
        half8 vn1 = *(const half8*)&Vb[(size_t)(16 + mm) * NHW + jv + q * 8];

        // PV for iteration it-1 (P read issued last iteration; V retained)
        #pragma unroll
        for (int qt = 0; qt < 4; qt++) {
            oa[qt][0] = __builtin_amdgcn_mfma_f32_16x16x32_f16(vp0, pf[qt], oa[qt][0], 0, 0, 0);
            oa[qt][1] = __builtin_amdgcn_mfma_f32_16x16x32_f16(vp1, pf[qt], oa[qt][1], 0, 0, 0);
        }

        int buf = it & 1;
        #pragma unroll
        for (int qt = 0; qt < 4; qt++) {
            float e0 = exp2f(s[qt][0][0]), e1 = exp2f(s[qt][0][1]);
            float e2 = exp2f(s[qt][0][2]), e3 = exp2f(s[qt][0][3]);
            float f0 = exp2f(s[qt][1][0]), f1 = exp2f(s[qt][1][1]);
            float f2 = exp2f(s[qt][1][2]), f3 = exp2f(s[qt][1][3]);
            dd[qt] += ((e0 + e1) + (e2 + e3)) + ((f0 + f1) + (f2 + f3));
            half_t (*PB)[36] = Pl[wv][qt][buf];
            st8h(&PB[mm][q * 4],      pk2(e0, e1), pk2(e2, e3));
            st8h(&PB[mm][16 + q * 4], pk2(f0, f1), pk2(f2, f3));
        }
        // read back P^T B-fragments as two 8B reads (stride 72B is 8B-aligned)
        #pragma unroll
        for (int qt = 0; qt < 4; qt++) {
            union { half4v h4[2]; half8 h8; } u;
            u.h4[0] = *(half4v*)&Pl[wv][qt][buf][mm][q * 8];
            u.h4[1] = *(half4v*)&Pl[wv][qt][buf][mm][q * 8 + 4];
            pf[qt] = u.h8;
        }

        kc0 = kn0; kc1 = kn1; kn0 = kf0; kn1 = kf1;
        vp0 = vc0; vp1 = vc1; vc0 = vn0; vc1 = vn1;
    }
    #pragma unroll
    for (int qt = 0; qt < 4; qt++) {
        oa[qt][0] = __builtin_amdgcn_mfma_f32_16x16x32_f16(vp0, pf[qt], oa[qt][0], 0, 0, 0);
        oa[qt][1] = __builtin_amdgcn_mfma_f32_16x16x32_f16(vp1, pf[qt], oa[qt][1], 0, 0, 0);
    }

    #pragma unroll
    for (int qt = 0; qt < 4; qt++) {
        dd[qt] += __shfl_xor(dd[qt], 16);
        dd[qt] += __shfl_xor(dd[qt], 32);
    }

    #pragma unroll
    for (int qt = 0; qt < 4; qt++)
        #pragma unroll
        for (int r = 0; r < 4; r++) {
            Oz[wv][q * 4 + r][qt * 16 + mm]      = oa[qt][0][r];
            Oz[wv][16 + q * 4 + r][qt * 16 + mm] = oa[qt][1][r];
        }
    if (q == 0) {
        #pragma unroll
        for (int qt = 0; qt < 4; qt++) Dz[wv][qt * 16 + mm] = dd[qt];
    }
    __syncthreads();

    int t = threadIdx.x;
    int iloc = t >> 2, dg = t & 3;  // 64 queries x 4 groups of 8 d
    float den = (Dz[0][iloc] + Dz[1][iloc]) + (Dz[2][iloc] + Dz[3][iloc]);
    float rinv = 1.f / den;
    float v[8];
    #pragma unroll
    for (int r = 0; r < 8; r++) {
        int d = dg * 8 + r;
        v[r] = ((Oz[0][d][iloc] + Oz[1][d][iloc]) + (Oz[2][d][iloc] + Oz[3][d][iloc])) * rinv;
    }
    half_t* dst = At + ((size_t)b * NHW + i0 + iloc) * NC + h * HD + dg * 8;
    st8h(dst,     pk2(v[0], v[1]), pk2(v[2], v[3]));
    st8h(dst + 4, pk2(v[4], v[5]), pk2(v[6], v[7]));
}

// ---------------- fused output projection + residual + LayerNorm ----------------
// grid (32, 8) = 256 blocks (1/CU), 512 thr / 8 waves. s-tile 32: halves Wp L2 re-reads.
// Wave w: o-range (w&3)*64, k-half (w>>2)*128.
__global__ __launch_bounds__(512) void projln(
    const half_t* __restrict__ At, const half_t* __restrict__ Wph,
    const float* __restrict__ bp, const float* __restrict__ x,
    const float* __restrict__ gamma, const float* __restrict__ beta,
    float* __restrict__ outp)
{
    __shared__ float tile[32][273];   // [s][c]
    __shared__ float xs[256][33];     // coalesced-staged residual [c][s]
    __shared__ float Pz[4][64][33];   // upper-k-half partials [o-wave][o_loc][s]
    __shared__ float ps[16][32], ps2[16][32];
    __shared__ float mu_s[32], rs_s[32];

    int t = threadIdx.x, wv = t >> 6, lane = t & 63;
    int mm = lane & 15, q = lane >> 4;
    int oh = wv & 3, kh = wv >> 2;
    int o0 = oh * 64;
    int b = blockIdx.y, s0 = blockIdx.x * 32;
    const half_t* ab = At + (size_t)b * NHW * NC;

    {
        int sL = t & 31, cb = t >> 5;  // 16 c-rows per pass
        #pragma unroll
        for (int pass = 0; pass < 16; pass++) {
            int c = pass * 16 + cb;
            xs[c][sL] = x[((size_t)b * NC + c) * NHW + s0 + sL];
        }
    }

    floatx4 acc[4][2];
    #pragma unroll
    for (int mt = 0; mt < 4; mt++)
        #pragma unroll
        for (int nt = 0; nt < 2; nt++) acc[mt][nt] = (floatx4){0.f, 0.f, 0.f, 0.f};

    int kbase = kh * 128;
    #pragma unroll
    for (int kk = 0; kk < 128; kk += 32) {
        int k0 = kbase + kk;
        half8 bf[2];
        #pragma unroll
        for (int nt = 0; nt < 2; nt++)
            bf[nt] = *(const half8*)&ab[(size_t)(s0 + nt * 16 + mm) * NC + k0 + q * 8];
        #pragma unroll
        for (int mt = 0; mt < 4; mt++) {
            half8 af = *(const half8*)&Wph[(size_t)(o0 + mt * 16 + mm) * NC + k0 + q * 8];
            #pragma unroll
            for (int nt = 0; nt < 2; nt++)
                acc[mt][nt] = __builtin_amdgcn_mfma_f32_16x16x32_f16(af, bf[nt], acc[mt][nt], 0, 0, 0);
        }
    }

    if (kh == 1) {
        #pragma unroll
        for (int mt = 0; mt < 4; mt++)
            #pragma unroll
            for (int nt = 0; nt < 2; nt++)
                #pragma unroll
                for (int r = 0; r < 4; r++)
                    Pz[oh][mt * 16 + q * 4 + r][nt * 16 + mm] = acc[mt][nt][r];
    }
    __syncthreads();
    if (kh == 0) {
        #pragma unroll
        for (int mt = 0; mt < 4; mt++) {
            #pragma unroll
            for (int nt = 0; nt < 2; nt++) {
                #pragma unroll
                for (int r = 0; r < 4; r++) {
                    int ol = mt * 16 + q * 4 + r;
                    int o = o0 + ol;
                    int sl = nt * 16 + mm;
                    tile[sl][o] = acc[mt][nt][r] + Pz[oh][ol][sl] + bp[o] + xs[o][sl];
                }
            }
        }
    }
    __syncthreads();

    int sL = t & 31, part = t >> 5;  // 16 parts of 16 channels
    float sum = 0.f, sq = 0.f;
    #pragma unroll
    for (int cc = 0; cc < 16; cc++) {
        float v = tile[sL][part * 16 + cc];
        sum += v; sq += v * v;
    }
    ps[part][sL] = sum; ps2[part][sL] = sq;
    __syncthreads();
    if (t < 32) {
        float S = 0.f, S2 = 0.f;
        #pragma unroll
        for (int p2 = 0; p2 < 16; p2++) { S += ps[p2][t]; S2 += ps2[p2][t]; }
        float mu  = S * (1.f / NC);
        float var = S2 * (1.f / NC) - mu * mu;
        mu_s[t] = mu;
        rs_s[t] = rsqrtf(var + 1e-5f);
    }
    __syncthreads();
    float mu = mu_s[sL], rs = rs_s[sL];
    float* ob = outp + (size_t)b * NC * NHW;
    #pragma unroll
    for (int cc = 0; cc < 16; cc++) {
        int c = part * 16 + cc;
        ob[(size_t)c * NHW + s0 + sL] = (tile[sL][c] - mu) * rs * gamma[c] + beta[c];
    }
}

extern "C" void kernel_launch(void* const* d_in, const int* in_sizes, int n_in,
                              void* d_out, int out_size, void* d_ws, size_t ws_size,
                              hipStream_t stream)
{
    const float* x     = (const float*)d_in[0];
    const float* Wq    = (const float*)d_in[1];
    const float* bq    = (const float*)d_in[2];
    const float* Wk    = (const float*)d_in[3];
    const float* bk    = (const float*)d_in[4];
    const float* Wv    = (const float*)d_in[5];
    const float* bv    = (const float*)d_in[6];
    const float* Wp    = (const float*)d_in[7];
    const float* bp    = (const float*)d_in[8];
    const float* gamma = (const float*)d_in[9];
    const float* beta  = (const float*)d_in[10];
    float* out = (float*)d_out;

    char* w = (char*)d_ws;
    half_t* Qt = (half_t*)(w);                       // 4 MB [bh][s][d]
    half_t* Kt = (half_t*)(w + ((size_t)4  << 20));  // 4 MB [bh][s][d]
    half_t* Vv = (half_t*)(w + ((size_t)8  << 20));  // 4 MB [bh][d][s]
    half_t* At = (half_t*)(w + ((size_t)12 << 20));  // 4 MB [b][s][c]
    half_t* Wh = (half_t*)(w + ((size_t)16 << 20));  // 512 KB f16 weights [q][k][v][p]

    wprep<<<dim3(128), 256, 0, stream>>>(Wq, Wk, Wv, Wp, Wh);
    qkv_mfma<<<dim3(16, 1, 24), 512, 0, stream>>>(x, Wh, bq, bk, bv, Qt, Kt, Vv);
    attn_mfma<<<dim3(1024), 256, 0, stream>>>(Qt, Kt, Vv, At);
    projln<<<dim3(32, 8), 512, 0, stream>>>(At, Wh + 3 * 65536, bp, x, gamma, beta, out);
}

// Round 12
// 128.053 us; speedup vs baseline: 1.2945x; 1.0009x over previous
//
#include <hip/hip_runtime.h>
#include <math.h>

#define NB 8
#define NC 256
#define NHW 1024
#define NHEADS 8
#define HD 32

typedef _Float16 half_t;
typedef __attribute__((ext_vector_type(8))) _Float16 half8;
typedef __attribute__((ext_vector_type(4))) _Float16 half4v;
typedef __attribute__((ext_vector_type(2))) _Float16 half2v;
typedef __attribute__((ext_vector_type(4))) float floatx4;

__device__ __forceinline__ half2v pk2(float a, float b) {
    union {
        __fp16 __attribute__((ext_vector_type(2))) r;
        half2v h;
    } u;
    u.r = __builtin_amdgcn_cvt_pkrtz(a, b);  // v_cvt_pkrtz_f16_f32
    return u.h;
}
__device__ __forceinline__ void st8h(half_t* p, half2v a, half2v b) {
    union { half2v h[2]; uint2 u; } t;
    t.h[0] = a; t.h[1] = b;
    *(uint2*)p = t.u;  // 8B store, p must be 8B-aligned
}

// ---------------- weight prep: fp32 -> f16 once (Wq pre-scaled by 1/sqrt(32)*log2e) ----
// 4 matrices of 256x256 contiguous in Wh: [q][k][v][p]. 1 MB read, 512 KB write, ~3 us.
__global__ __launch_bounds__(256) void wprep(
    const float* __restrict__ Wq, const float* __restrict__ Wk,
    const float* __restrict__ Wv, const float* __restrict__ Wp,
    half_t* __restrict__ Wh)
{
    int t = blockIdx.x * 256 + threadIdx.x;  // 128 blocks * 256 thr * 8 elems = 262144
    int e = t * 8;
    int m = e >> 16, off = e & 65535;
    const float* src = (m == 0) ? Wq : (m == 1) ? Wk : (m == 2) ? Wv : Wp;
    float sc = (m == 0) ? 0.17677669529663687f * 1.4426950408889634f : 1.f;
    float4 a = *(const float4*)(src + off);
    float4 b = *(const float4*)(src + off + 4);
    union { half2v h2[4]; half8 h8; } u;
    u.h2[0] = pk2(a.x * sc, a.y * sc);
    u.h2[1] = pk2(a.z * sc, a.w * sc);
    u.h2[2] = pk2(b.x * sc, b.y * sc);
    u.h2[3] = pk2(b.z * sc, b.w * sc);
    *(half8*)&Wh[e] = u.h8;
}

// ---------------- QKV: 64-wide s-tile, one p per block, W panel hoisted to regs --------
// grid (16, 1, 24), 512 thr / 8 waves. bz = b + 8*p. NEW vs R3: the wave's entire W
// panel (16 half8 = 64 VGPR) is loaded BEFORE x staging, so W L2 latency overlaps the
// staging phase and the k-loop runs pure LDS+MFMA (no global latency on critical path).
__global__ __launch_bounds__(512) void qkv_mfma(
    const float* __restrict__ x, const half_t* __restrict__ Wh,
    const float* __restrict__ bq, const float* __restrict__ bk, const float* __restrict__ bv,
    half_t* __restrict__ Qt, half_t* __restrict__ Kt, half_t* __restrict__ Vv)
{
    // [s][c], stride 264. 8-half blocks XOR-swizzled by ((s>>2)&7): staging b32 writes
    // land 2 lanes/bank (free); b128 reads keep ~2-way.
    __shared__ half_t xs[64][264];

    int bz = blockIdx.z;
    int b = bz & 7, p = bz >> 3;  // wave-uniform
    const half_t* Wf    = Wh + (size_t)p * 65536;
    const float*  bias  = (p == 0) ? bq : (p == 1) ? bk : bv;

    int t = threadIdx.x;
    int s0 = blockIdx.x * 64;
    const float* xb = x + (size_t)b * NC * NHW;

    int wv = t >> 6, lane = t & 63;
    int mm = lane & 15, q = lane >> 4;
    int o0 = wv * 32;  // wave wv == head wv

    // prefetch the wave's whole W panel (2 rows x 8 k-blocks) into registers; these
    // loads are independent of LDS and issue ahead of / alongside the staging loads.
    half8 af[8][2];
    #pragma unroll
    for (int kk = 0; kk < 8; kk++)
        #pragma unroll
        for (int mt = 0; mt < 2; mt++)
            af[kk][mt] = *(const half8*)&Wf[(size_t)(o0 + mt * 16 + mm) * NC + kk * 32 + q * 8];

    // stage + transpose + convert: pairs of c rows -> half2 LDS writes (swizzled)
    {
        int sf = t & 15, cp = t >> 4;  // sf: s-group (4 floats), cp: c-pair 0..31
        int sw = (sf & 7) << 3;        // XOR on 8-half block index (bits 3..5 of col)
        #pragma unroll
        for (int pass = 0; pass < 4; pass++) {
            int c = cp * 2 + 64 * pass;
            int cw = c ^ sw;           // c even, sw bits>=3: stays even, 4B-aligned
            float4 a  = *(const float4*)&xb[(size_t)c * NHW + s0 + sf * 4];
            float4 bb = *(const float4*)&xb[(size_t)(c + 1) * NHW + s0 + sf * 4];
            *(half2v*)&xs[sf * 4 + 0][cw] = pk2(a.x, bb.x);
            *(half2v*)&xs[sf * 4 + 1][cw] = pk2(a.y, bb.y);
            *(half2v*)&xs[sf * 4 + 2][cw] = pk2(a.z, bb.z);
            *(half2v*)&xs[sf * 4 + 3][cw] = pk2(a.w, bb.w);
        }
    }
    __syncthreads();

    floatx4 acc[2][4];
    #pragma unroll
    for (int mt = 0; mt < 2; mt++)
        #pragma unroll
        for (int nt = 0; nt < 4; nt++) acc[mt][nt] = (floatx4){0.f, 0.f, 0.f, 0.f};

    #pragma unroll
    for (int kk = 0; kk < 8; kk++) {
        int k0 = kk * 32;
        half8 bf[4];
        #pragma unroll
        for (int nt = 0; nt < 4; nt++) {
            int row = nt * 16 + mm;
            int col = (k0 + q * 8) ^ (((row >> 2) & 7) << 3);  // same swizzle as writes
            bf[nt] = *(const half8*)&xs[row][col];
        }
        #pragma unroll
        for (int mt = 0; mt < 2; mt++)
            #pragma unroll
            for (int nt = 0; nt < 4; nt++)
                acc[mt][nt] = __builtin_amdgcn_mfma_f32_16x16x32_f16(af[kk][mt], bf[nt], acc[mt][nt], 0, 0, 0);
    }

    int h  = wv;
    int bh = b * NHEADS + h;
    // Wq was pre-scaled by qs at prep; bias for p==0 must get the same scale.
    const float qs = 0.17677669529663687f * 1.4426950408889634f;
    float bsc = (p == 0) ? qs : 1.f;

    #pragma unroll
    for (int mt = 0; mt < 2; mt++) {
        int d0 = mt * 16 + q * 4;  // d within head
        float bb[4];
        #pragma unroll
        for (int r = 0; r < 4; r++) bb[r] = bias[o0 + mt * 16 + q * 4 + r] * bsc;
        #pragma unroll
        for (int nt = 0; nt < 4; nt++) {
            int s = s0 + nt * 16 + mm;
            float v0 = acc[mt][nt][0] + bb[0], v1 = acc[mt][nt][1] + bb[1];
            float v2 = acc[mt][nt][2] + bb[2], v3 = acc[mt][nt][3] + bb[3];
            if (p < 2) {
                half_t* out = (p == 0 ? Qt : Kt) + ((size_t)bh * NHW + s) * HD + d0;
                st8h(out, pk2(v0, v1), pk2(v2, v3));
            } else {
                Vv[((size_t)bh * HD + d0 + 0) * NHW + s] = (half_t)v0;
                Vv[((size_t)bh * HD + d0 + 1) * NHW + s] = (half_t)v1;
                Vv[((size_t)bh * HD + d0 + 2) * NHW + s] = (half_t)v2;
                Vv[((size_t)bh * HD + d0 + 3) * NHW + s] = (half_t)v3;
            }
        }
    }
}

// ---------------- fused attention (exact round-7/11 best): S^T, j-split, 64 q/block ----
// grid 1024: bh = L&63 (8-head K/V per XCD, L2-resident), iblk = L>>6.
// 4 waves each own a 256-key quarter; lagged reg pipeline (pf/vp); double-buffered Pl;
// per-wave Oz/Dz stores + cross-wave reduce epilogue. Measured best (128.2 total).
__global__ __launch_bounds__(256) void attn_mfma(
    const half_t* __restrict__ Qt, const half_t* __restrict__ Kt,
    const half_t* __restrict__ Vv, half_t* __restrict__ At)
{
    __shared__ half_t Pl[4][4][2][16][36];  // [wave][qt][buf][i][j] ~36 KB
    __shared__ float Oz[4][32][66];         // [wave][d][i] stride 66: 2-way max ~34 KB
    __shared__ float Dz[4][64];             // [wave][i]

    int wv = threadIdx.x >> 6, lane = threadIdx.x & 63;
    int mm = lane & 15, q = lane >> 4;
    int L = blockIdx.x;
    int bh = L & 63, iblk = L >> 6;
    int b = bh >> 3, h = bh & 7;
    int i0 = iblk * 64;

    const half_t* Qb = Qt + (size_t)bh * NHW * HD;
    const half_t* Kb = Kt + (size_t)bh * NHW * HD;
    const half_t* Vb = Vv + (size_t)bh * HD * NHW;

    half8 qf[4];
    #pragma unroll
    for (int qt = 0; qt < 4; qt++)
        qf[qt] = *(const half8*)&Qb[(size_t)(i0 + qt * 16 + mm) * HD + q * 8];

    const int jb = wv * 256;  // this wave's key quarter
    floatx4 zero = (floatx4){0.f, 0.f, 0.f, 0.f};
    floatx4 oa[4][2];
    #pragma unroll
    for (int qt = 0; qt < 4; qt++) { oa[qt][0] = zero; oa[qt][1] = zero; }
    float dd[4] = {0.f, 0.f, 0.f, 0.f};
    const _Float16 z = (_Float16)0.f;
    half8 pf[4];
    #pragma unroll
    for (int qt = 0; qt < 4; qt++) pf[qt] = (half8){z, z, z, z, z, z, z, z};

    half8 kc0 = *(const half8*)&Kb[(size_t)(jb + mm) * HD + q * 8];
    half8 kc1 = *(const half8*)&Kb[(size_t)(jb + 16 + mm) * HD + q * 8];
    half8 kn0 = *(const half8*)&Kb[(size_t)(jb + 32 + mm) * HD + q * 8];
    half8 kn1 = *(const half8*)&Kb[(size_t)(jb + 48 + mm) * HD + q * 8];
    half8 vc0 = *(const half8*)&Vb[(size_t)mm * NHW + jb + q * 8];
    half8 vc1 = *(const half8*)&Vb[(size_t)(16 + mm) * NHW + jb + q * 8];
    half8 vp0 = vc0, vp1 = vc1;

    #pragma unroll
    for (int it = 0; it < 8; it++) {
        floatx4 s[4][2];
        #pragma unroll
        for (int qt = 0; qt < 4; qt++) {
            s[qt][0] = __builtin_amdgcn_mfma_f32_16x16x32_f16(kc0, qf[qt], zero, 0, 0, 0);
            s[qt][1] = __builtin_amdgcn_mfma_f32_16x16x32_f16(kc1, qf[qt], zero, 0, 0, 0);
        }

        int jk = jb + ((it + 2) & 7) * 32;
        int jv = jb + ((it + 1) & 7) * 32;
        half8 kf0 = *(const half8*)&Kb[(size_t)(jk + mm) * HD + q * 8];
        half8 kf1 = *(const half8*)&Kb[(size_t)(jk + 16 + mm) * HD + q * 8];
        half8 vn0 = *(const half8*)&Vb[(size_t)mm * NHW + jv + q * 8];
        half8 vn1 = *(const half8*)&Vb[(size_t)(16 + mm) * NHW + jv + q * 8];

        // PV for iteration it-1 (P read issued last iteration; V retained)
        #pragma unroll
        for (int qt = 0; qt < 4; qt++) {
            oa[qt][0] = __builtin_amdgcn_mfma_f32_16x16x32_f16(vp0, pf[qt], oa[qt][0], 0, 0, 0);
            oa[qt][1] = __builtin_amdgcn_mfma_f32_16x16x32_f16(vp1, pf[qt], oa[qt][1], 0, 0, 0);
        }

        int buf = it & 1;
        #pragma unroll
        for (int qt = 0; qt < 4; qt++) {
            float e0 = exp2f(s[qt][0][0]), e1 = exp2f(s[qt][0][1]);
            float e2 = exp2f(s[qt][0][2]), e3 = exp2f(s[qt][0][3]);
            float f0 = exp2f(s[qt][1][0]), f1 = exp2f(s[qt][1][1]);
            float f2 = exp2f(s[qt][1][2]), f3 = exp2f(s[qt][1][3]);
            dd[qt] += ((e0 + e1) + (e2 + e3)) + ((f0 + f1) + (f2 + f3));
            half_t (*PB)[36] = Pl[wv][qt][buf];
            st8h(&PB[mm][q * 4],      pk2(e0, e1), pk2(e2, e3));
            st8h(&PB[mm][16 + q * 4], pk2(f0, f1), pk2(f2, f3));
        }
        // read back P^T B-fragments as two 8B reads (stride 72B is 8B-aligned)
        #pragma unroll
        for (int qt = 0; qt < 4; qt++) {
            union { half4v h4[2]; half8 h8; } u;
            u.h4[0] = *(half4v*)&Pl[wv][qt][buf][mm][q * 8];
            u.h4[1] = *(half4v*)&Pl[wv][qt][buf][mm][q * 8 + 4];
            pf[qt] = u.h8;
        }

        kc0 = kn0; kc1 = kn1; kn0 = kf0; kn1 = kf1;
        vp0 = vc0; vp1 = vc1; vc0 = vn0; vc1 = vn1;
    }
    #pragma unroll
    for (int qt = 0; qt < 4; qt++) {
        oa[qt][0] = __builtin_amdgcn_mfma_f32_16x16x32_f16(vp0, pf[qt], oa[qt][0], 0, 0, 0);
        oa[qt][1] = __builtin_amdgcn_mfma_f32_16x16x32_f16(vp1, pf[qt], oa[qt][1], 0, 0, 0);
    }

    #pragma unroll
    for (int qt = 0; qt < 4; qt++) {
        dd[qt] += __shfl_xor(dd[qt], 16);
        dd[qt] += __shfl_xor(dd[qt], 32);
    }

    #pragma unroll
    for (int qt = 0; qt < 4; qt++)
        #pragma unroll
        for (int r = 0; r < 4; r++) {
            Oz[wv][q * 4 + r][qt * 16 + mm]      = oa[qt][0][r];
            Oz[wv][16 + q * 4 + r][qt * 16 + mm] = oa[qt][1][r];
        }
    if (q == 0) {
        #pragma unroll
        for (int qt = 0; qt < 4; qt++) Dz[wv][qt * 16 + mm] = dd[qt];
    }
    __syncthreads();

    int t = threadIdx.x;
    int iloc = t >> 2, dg = t & 3;  // 64 queries x 4 groups of 8 d
    float den = (Dz[0][iloc] + Dz[1][iloc]) + (Dz[2][iloc] + Dz[3][iloc]);
    float rinv = 1.f / den;
    float v[8];
    #pragma unroll
    for (int r = 0; r < 8; r++) {
        int d = dg * 8 + r;
        v[r] = ((Oz[0][d][iloc] + Oz[1][d][iloc]) + (Oz[2][d][iloc] + Oz[3][d][iloc])) * rinv;
    }
    half_t* dst = At + ((size_t)b * NHW + i0 + iloc) * NC + h * HD + dg * 8;
    st8h(dst,     pk2(v[0], v[1]), pk2(v[2], v[3]));
    st8h(dst + 4, pk2(v[4], v[5]), pk2(v[6], v[7]));
}

// ---------------- fused output projection + residual + LayerNorm ----------------
// grid (32, 8) = 256 blocks (1/CU), 512 thr / 8 waves. s-tile 32.
// NEW: per-wave Wph panel (16 half8) + At fragments (8 half8) hoisted into registers
// before xs staging — all 24 global loads issue together, MFMA loop runs from regs.
__global__ __launch_bounds__(512) void projln(
    const half_t* __restrict__ At, const half_t* __restrict__ Wph,
    const float* __restrict__ bp, const float* __restrict__ x,
    const float* __restrict__ gamma, const float* __restrict__ beta,
    float* __restrict__ outp)
{
    __shared__ float tile[32][273];   // [s][c]
    __shared__ float xs[256][33];     // coalesced-staged residual [c][s]
    __shared__ float Pz[4][64][33];   // upper-k-half partials [o-wave][o_loc][s]
    __shared__ float ps[16][32], ps2[16][32];
    __shared__ float mu_s[32], rs_s[32];

    int t = threadIdx.x, wv = t >> 6, lane = t & 63;
    int mm = lane & 15, q = lane >> 4;
    int oh = wv & 3, kh = wv >> 2;
    int o0 = oh * 64;
    int b = blockIdx.y, s0 = blockIdx.x * 32;
    const half_t* ab = At + (size_t)b * NHW * NC;
    int kbase = kh * 128;

    // prefetch W panel and At fragments into registers (issue before staging)
    half8 wf[4][4];  // [kk][mt]
    #pragma unroll
    for (int kk = 0; kk < 4; kk++)
        #pragma unroll
        for (int mt = 0; mt < 4; mt++)
            wf[kk][mt] = *(const half8*)&Wph[(size_t)(o0 + mt * 16 + mm) * NC + kbase + kk * 32 + q * 8];
    half8 bf[4][2];  // [kk][nt]
    #pragma unroll
    for (int kk = 0; kk < 4; kk++)
        #pragma unroll
        for (int nt = 0; nt < 2; nt++)
            bf[kk][nt] = *(const half8*)&ab[(size_t)(s0 + nt * 16 + mm) * NC + kbase + kk * 32 + q * 8];

    {
        int sL = t & 31, cb = t >> 5;  // 16 c-rows per pass
        #pragma unroll
        for (int pass = 0; pass < 16; pass++) {
            int c = pass * 16 + cb;
            xs[c][sL] = x[((size_t)b * NC + c) * NHW + s0 + sL];
        }
    }

    floatx4 acc[4][2];
    #pragma unroll
    for (int mt = 0; mt < 4; mt++)
        #pragma unroll
        for (int nt = 0; nt < 2; nt++) acc[mt][nt] = (floatx4){0.f, 0.f, 0.f, 0.f};

    #pragma unroll
    for (int kk = 0; kk < 4; kk++)
        #pragma unroll
        for (int mt = 0; mt < 4; mt++)
            #pragma unroll
            for (int nt = 0; nt < 2; nt++)
                acc[mt][nt] = __builtin_amdgcn_mfma_f32_16x16x32_f16(wf[kk][mt], bf[kk][nt], acc[mt][nt], 0, 0, 0);

    if (kh == 1) {
        #pragma unroll
        for (int mt = 0; mt < 4; mt++)
            #pragma unroll
            for (int nt = 0; nt < 2; nt++)
                #pragma unroll
                for (int r = 0; r < 4; r++)
                    Pz[oh][mt * 16 + q * 4 + r][nt * 16 + mm] = acc[mt][nt][r];
    }
    __syncthreads();
    if (kh == 0) {
        #pragma unroll
        for (int mt = 0; mt < 4; mt++) {
            #pragma unroll
            for (int nt = 0; nt < 2; nt++) {
                #pragma unroll
                for (int r = 0; r < 4; r++) {
                    int ol = mt * 16 + q * 4 + r;
                    int o = o0 + ol;
                    int sl = nt * 16 + mm;
                    tile[sl][o] = acc[mt][nt][r] + Pz[oh][ol][sl] + bp[o] + xs[o][sl];
                }
            }
        }
    }
    __syncthreads();

    int sL = t & 31, part = t >> 5;  // 16 parts of 16 channels
    float sum = 0.f, sq = 0.f;
    #pragma unroll
    for (int cc = 0; cc < 16; cc++) {
        float v = tile[sL][part * 16 + cc];
        sum += v; sq += v * v;
    }
    ps[part][sL] = sum; ps2[part][sL] = sq;
    __syncthreads();
    if (t < 32) {
        float S = 0.f, S2 = 0.f;
        #pragma unroll
        for (int p2 = 0; p2 < 16; p2++) { S += ps[p2][t]; S2 += ps2[p2][t]; }
        float mu  = S * (1.f / NC);
        float var = S2 * (1.f / NC) - mu * mu;
        mu_s[t] = mu;
        rs_s[t] = rsqrtf(var + 1e-5f);
    }
    __syncthreads();
    float mu = mu_s[sL], rs = rs_s[sL];
    float* ob = outp + (size_t)b * NC * NHW;
    #pragma unroll
    for (int cc = 0; cc < 16; cc++) {
        int c = part * 16 + cc;
        ob[(size_t)c * NHW + s0 + sL] = (tile[sL][c] - mu) * rs * gamma[c] + beta[c];
    }
}

extern "C" void kernel_launch(void* const* d_in, const int* in_sizes, int n_in,
                              void* d_out, int out_size, void* d_ws, size_t ws_size,
                              hipStream_t stream)
{
    const float* x     = (const float*)d_in[0];
    const float* Wq    = (const float*)d_in[1];
    const float* bq    = (const float*)d_in[2];
    const float* Wk    = (const float*)d_in[3];
    const float* bk    = (const float*)d_in[4];
    const float* Wv    = (const float*)d_in[5];
    const float* bv    = (const float*)d_in[6];
    const float* Wp    = (const float*)d_in[7];
    const float* bp    = (const float*)d_in[8];
    const float* gamma = (const float*)d_in[9];
    const float* beta  = (const float*)d_in[10];
    float* out = (float*)d_out;

    char* w = (char*)d_ws;
    half_t* Qt = (half_t*)(w);                       // 4 MB [bh][s][d]
    half_t* Kt = (half_t*)(w + ((size_t)4  << 20));  // 4 MB [bh][s][d]
    half_t* Vv = (half_t*)(w + ((size_t)8  << 20));  // 4 MB [bh][d][s]
    half_t* At = (half_t*)(w + ((size_t)12 << 20));  // 4 MB [b][s][c]
    half_t* Wh = (half_t*)(w + ((size_t)16 << 20));  // 512 KB f16 weights [q][k][v][p]

    wprep<<<dim3(128), 256, 0, stream>>>(Wq, Wk, Wv, Wp, Wh);
    qkv_mfma<<<dim3(16, 1, 24), 512, 0, stream>>>(x, Wh, bq, bk, bv, Qt, Kt, Vv);
    attn_mfma<<<dim3(1024), 256, 0, stream>>>(Qt, Kt, Vv, At);
    projln<<<dim3(32, 8), 512, 0, stream>>>(At, Wh + 3 * 65536, bp, x, gamma, beta, out);
}